// Round 3
// baseline (1316.266 us; speedup 1.0000x reference)
//
#include <hip/hip_runtime.h>
#include <hip/hip_bf16.h>
#include <hip/hip_fp16.h>

#define Bn 256
#define Sn 1024
#define Hn 256
#define Vn 128
#define En 128

typedef _Float16 f16x8 __attribute__((ext_vector_type(8)));
typedef _Float16 f16x4 __attribute__((ext_vector_type(4)));
typedef float f32x4 __attribute__((ext_vector_type(4)));

// swizzles (byte-offset bijections; XOR bits chosen to keep b64/b128 alignment)
__device__ __forceinline__ int t2_swz(int b) { return b ^ (((b >> 7) & 3) << 3); }
__device__ __forceinline__ int a_swz(int b)  { return b ^ (((b >> 9) & 7) << 4); }
// k-permutation (involution): p = ((k&15)<<4) | (k>>4)
__device__ __forceinline__ int kswap(int k)  { return ((k & 15) << 4) | (k >> 4); }

// ---------- Kernel B: MFMA recurrence. 16 blocks (16 batch rows each), 256 threads (4 waves).
// Wave w owns output cols [64w, 64w+64) (4 col-blocks of 16). W_hh f16 B-frags stationary
// in registers. h tile [16][256] f16 double-buffered in LDS (k-index nibble-swapped +
// XOR-swizzled). x = emb/W_ih table, f16, LDS-resident (computed in prologue). One
// barrier per step. MFMA accumulate in f32; tanh in f32.
__global__ __launch_bounds__(256, 1) void k_rnn(const int* __restrict__ inp,
    const float* __restrict__ hidden, const float* __restrict__ emb,
    const float* __restrict__ W_ih, const float* __restrict__ b_ih,
    const float* __restrict__ W_hh, const float* __restrict__ b_hh,
    float* out_base) {
  __shared__ _Float16 T2l[Vn * Hn];        // 64 KB, [v][kswap(h)] + t2_swz
  __shared__ _Float16 Abuf[2 * 16 * Hn];   // 16 KB, [m][kswap(k)] + a_swz, double-buffered

  const int tid = threadIdx.x;
  const int l = tid & 63;
  const int w = tid >> 6;        // 0..3
  const int g = l >> 4;          // 0..3
  const int c = l & 15;
  const int bb0 = blockIdx.x << 4;

  // ---- Prologue 1: T2l[v][kswap(h)] = emb[v]·W_ih[h] + b_ih[h] + b_hh[h]  (f16)
  {
    const int v = tid >> 1;
    const int h0 = (tid & 1) << 7;
    float er[En];
    #pragma unroll
    for (int i = 0; i < En / 4; ++i) {
      float4 t4 = ((const float4*)(emb + v * En))[i];
      er[4*i] = t4.x; er[4*i+1] = t4.y; er[4*i+2] = t4.z; er[4*i+3] = t4.w;
    }
    for (int hh = 0; hh < 128; ++hh) {
      int h = h0 + hh;
      const float4* wr = (const float4*)(W_ih + h * En);
      float acc = 0.f;
      #pragma unroll
      for (int i = 0; i < En / 4; ++i) {
        float4 t4 = wr[i];
        acc += er[4*i] * t4.x + er[4*i+1] * t4.y + er[4*i+2] * t4.z + er[4*i+3] * t4.w;
      }
      acc += b_ih[h] + b_hh[h];
      int byte = t2_swz(v * 512 + kswap(h) * 2);
      *(_Float16*)((char*)T2l + byte) = (_Float16)acc;
    }
  }

  // ---- Prologue 2: W_hh B-frags (k-index permuted to match A storage)
  // Bf[cb][ks] elem j = W_hh[64w + 16cb + c][ kswap(32ks + 8g + j) ]
  f16x8 Bf[4][8];
  #pragma unroll
  for (int cb = 0; cb < 4; ++cb) {
    const float* wrow = W_hh + ((w << 6) + (cb << 4) + c) * Hn;
    #pragma unroll
    for (int ks = 0; ks < 8; ++ks) {
      union { _Float16 h[8]; f16x8 v8; } u;
      #pragma unroll
      for (int j = 0; j < 8; ++j) {
        int e = (ks << 5) + (g << 3) + j;
        u.h[j] = (_Float16)wrow[kswap(e)];
      }
      Bf[cb][ks] = u.v8;
    }
  }

  // ---- Prologue 3: initial hidden -> Abuf[buf0]
  #pragma unroll
  for (int r = 0; r < 4; ++r) {
    int m = (g << 2) + r;
    f16x4 pk;
    #pragma unroll
    for (int cb = 0; cb < 4; ++cb)
      pk[cb] = (_Float16)hidden[(bb0 + m) * Hn + (w << 6) + (cb << 4) + c];
    int byte = a_swz(m * 512 + c * 32 + (w << 3));
    *(unsigned long long*)((char*)Abuf + byte) = *(unsigned long long*)&pk;
  }
  __syncthreads();

  _Float16* hallp = (_Float16*)out_base;               // permuted f16 H_all overlay
  float* hfin = out_base + (size_t)Bn * Sn * Vn;       // h_final (true layout, f32)

  // x pipeline: xv = x(t), iv = idx(t+1)
  int iv[4];
  f16x4 xv[4];
  #pragma unroll
  for (int r = 0; r < 4; ++r)
    iv[r] = inp[(bb0 + (g << 2) + r) * Sn + 0];
  #pragma unroll
  for (int r = 0; r < 4; ++r) {
    int byte = t2_swz(iv[r] * 512 + c * 32 + (w << 3));
    xv[r] = *(const f16x4*)((const char*)T2l + byte);
    iv[r] = inp[(bb0 + (g << 2) + r) * Sn + ((Sn > 1) ? 1 : 0)];
  }

  float hcur[4][4];  // [cb][r], persists for h_final

  #pragma unroll 1
  for (int t = 0; t < Sn; ++t) {
    const int roff = (t & 1) ? 8192 : 0;       // read-buffer byte offset
    const int woff = 8192 - roff;              // write-buffer byte offset

    // prefetch x(t+1) from T2l using iv, then idx(t+2)
    f16x4 xn[4];
    int ivn[4];
    #pragma unroll
    for (int r = 0; r < 4; ++r) {
      int byte = t2_swz(iv[r] * 512 + c * 32 + (w << 3));
      xn[r] = *(const f16x4*)((const char*)T2l + byte);
    }
    int t2i = (t + 2 < Sn) ? (t + 2) : (Sn - 1);
    #pragma unroll
    for (int r = 0; r < 4; ++r)
      ivn[r] = inp[(bb0 + (g << 2) + r) * Sn + t2i];

    // frag reads + MFMA (A row m_a = c; permuted k consecutive)
    f32x4 acc[4] = {{0,0,0,0},{0,0,0,0},{0,0,0,0},{0,0,0,0}};
    const char* abase = (const char*)Abuf + roff;
    #pragma unroll
    for (int ks = 0; ks < 8; ++ks) {
      int byte = a_swz(c * 512 + (ks << 6) + (g << 4));
      f16x8 af = *(const f16x8*)(abase + byte);
      acc[0] = __builtin_amdgcn_mfma_f32_16x16x32_f16(af, Bf[0][ks], acc[0], 0, 0, 0);
      acc[1] = __builtin_amdgcn_mfma_f32_16x16x32_f16(af, Bf[1][ks], acc[1], 0, 0, 0);
      acc[2] = __builtin_amdgcn_mfma_f32_16x16x32_f16(af, Bf[2][ks], acc[2], 0, 0, 0);
      acc[3] = __builtin_amdgcn_mfma_f32_16x16x32_f16(af, Bf[3][ks], acc[3], 0, 0, 0);
    }

    // z, tanh, pack
    f16x4 hp[4];
    #pragma unroll
    for (int r = 0; r < 4; ++r) {
      #pragma unroll
      for (int cb = 0; cb < 4; ++cb) {
        float z = acc[cb][r] + (float)xv[r][cb];
        float e2 = __builtin_amdgcn_exp2f(z * 2.885390081777927f);
        float hn = fmaf(-2.f, __builtin_amdgcn_rcpf(e2 + 1.f), 1.f);
        hcur[cb][r] = hn;
        hp[r][cb] = (_Float16)hn;
      }
    }

    // write h(t+1) to the other buffer + export to global (permuted layout)
    char* wbase = (char*)Abuf + woff;
    #pragma unroll
    for (int r = 0; r < 4; ++r) {
      int m = (g << 2) + r;
      int byte = a_swz(m * 512 + c * 32 + (w << 3));
      *(unsigned long long*)(wbase + byte) = *(unsigned long long*)&hp[r];
      size_t eo = ((size_t)(bb0 + m) * Sn + t) * Hn + (c << 4) + (w << 2);
      *(f16x4*)(hallp + eo) = hp[r];
    }

    // rotate pipeline
    #pragma unroll
    for (int r = 0; r < 4; ++r) { xv[r] = xn[r]; iv[r] = ivn[r]; }

    __syncthreads();   // end-of-step: write-visibility for t+1 reads; WAR for t+1 writes
  }

  // h_final (true layout, f32)
  #pragma unroll
  for (int cb = 0; cb < 4; ++cb)
    #pragma unroll
    for (int r = 0; r < 4; ++r)
      hfin[(bb0 + (g << 2) + r) * Hn + (w << 6) + (cb << 4) + c] = hcur[cb][r];
}

// ---------- Kernel C: MFMA f16 GEMM over d_out (in place). Identical to round 2
// except W_ho fragments index k through kswap() to match the permuted H_all layout.
__global__ __launch_bounds__(512) void k_out(const float* __restrict__ W_ho,
    const float* __restrict__ b_ho, float* out_base) {
  __shared__ _Float16 Atile[64 * 256];  // 32 KB
  const int tid = threadIdx.x;
  const int l = tid & 63;
  const int w = tid >> 6;
  const size_t m0 = (size_t)blockIdx.x * 64;
  const _Float16* hall = (const _Float16*)out_base;

  {
    const uint4* src = (const uint4*)(hall + (m0 << 8));
    #pragma unroll
    for (int i = 0; i < 4; ++i) {
      int gg = tid + (i << 9);
      int row = gg >> 5;
      int cb = (gg & 31) << 4;
      uint4 d = src[gg];
      *(uint4*)((char*)Atile + row * 512 + (cb ^ ((row & 7) << 4))) = d;
    }
  }

  f16x8 Bf[8];
  {
    const int v = (w << 4) + (l & 15);
    const float* srcb = W_ho + v * Hn;
    #pragma unroll
    for (int ks = 0; ks < 8; ++ks) {
      union { _Float16 h[8]; f16x8 v8; } u;
      #pragma unroll
      for (int j = 0; j < 8; ++j) {
        int e = (ks << 5) + ((l >> 4) << 3) + j;
        u.h[j] = (_Float16)srcb[kswap(e)];
      }
      Bf[ks] = u.v8;
    }
  }
  const float bias = b_ho[(w << 4) + (l & 15)];
  __syncthreads();

  #pragma unroll
  for (int mt = 0; mt < 4; ++mt) {
    f32x4 acc = {bias, bias, bias, bias};
    const int row = (mt << 4) + (l & 15);
    #pragma unroll
    for (int ks = 0; ks < 8; ++ks) {
      int cb = ((ks << 5) + ((l >> 4) << 3)) << 1;
      f16x8 a = *(const f16x8*)((const char*)Atile + row * 512 + (cb ^ ((row & 7) << 4)));
      acc = __builtin_amdgcn_mfma_f32_16x16x32_f16(a, Bf[ks], acc, 0, 0, 0);
    }
    float* orow = out_base + (m0 + (mt << 4) + ((l >> 4) << 2)) * Vn + (w << 4) + (l & 15);
    orow[0]      = acc[0];
    orow[Vn]     = acc[1];
    orow[2 * Vn] = acc[2];
    orow[3 * Vn] = acc[3];
  }
}

extern "C" void kernel_launch(void* const* d_in, const int* in_sizes, int n_in,
                              void* d_out, int out_size, void* d_ws, size_t ws_size,
                              hipStream_t stream) {
  (void)in_sizes; (void)n_in; (void)out_size; (void)d_ws; (void)ws_size;
  const int*   inp    = (const int*)  d_in[0];
  const float* hidden = (const float*)d_in[1];
  const float* emb    = (const float*)d_in[2];
  const float* W_ih   = (const float*)d_in[3];
  const float* b_ih   = (const float*)d_in[4];
  const float* W_hh   = (const float*)d_in[5];
  const float* b_hh   = (const float*)d_in[6];
  const float* W_ho   = (const float*)d_in[7];
  const float* b_ho   = (const float*)d_in[8];
  float* out = (float*)d_out;

  k_rnn<<<dim3(Bn / 16), dim3(256), 0, stream>>>(inp, hidden, emb, W_ih, b_ih,
                                                 W_hh, b_hh, out);
  k_out<<<dim3((Bn * Sn) / 64), dim3(512), 0, stream>>>(W_ho, b_ho, out);
}

// Round 4
// 870.201 us; speedup vs baseline: 1.5126x; 1.5126x over previous
//
#include <hip/hip_runtime.h>
#include <hip/hip_bf16.h>
#include <hip/hip_fp16.h>

#define Bn 256
#define Sn 1024
#define Hn 256
#define Vn 128
#define En 128

typedef _Float16 f16x8 __attribute__((ext_vector_type(8)));
typedef _Float16 f16x4 __attribute__((ext_vector_type(4)));
typedef float f32x4 __attribute__((ext_vector_type(4)));
typedef unsigned long long u64;

// column permutation: n = 64w + 16cb + c  ->  k' = 64w + 4c + cb
// chosen so per-lane h-writes / x-reads are 4 contiguous f16 AND bank-pair == c
__device__ __forceinline__ int perm(int n) {
  return (n & 0xC0) | ((n & 15) << 2) | ((n >> 4) & 3);
}
__device__ __forceinline__ int iperm(int k) {
  return (k & 0xC0) | ((k & 3) << 4) | ((k >> 2) & 15);
}
// A-tile swizzle (row = byte>>9): XOR (row&7) into 16B-granule index
__device__ __forceinline__ int aswz(int b) { return b ^ (((b >> 9) & 7) << 4); }

__device__ __forceinline__ float tanh_fast(float z) {
  float e2 = __builtin_amdgcn_exp2f(z * 2.885390081777927f);
  return fmaf(-2.f, __builtin_amdgcn_rcpf(e2 + 1.f), 1.f);
}

// ---------- prep: T2g[v][perm(h)] = f16(emb[v]·W_ih[h] + b_ih[h] + b_hh[h]);
//                  Wp[v][k'] = f16(W_ho[v][iperm(k')])
__global__ void k_prep(const float* __restrict__ emb, const float* __restrict__ W_ih,
                       const float* __restrict__ b_ih, const float* __restrict__ b_hh,
                       const float* __restrict__ W_ho,
                       _Float16* __restrict__ T2g, _Float16* __restrict__ Wp) {
  int bid = blockIdx.x, tid = threadIdx.x;
  if (bid < Vn) {
    int vv = bid, h = tid;
    const float4* e4 = (const float4*)(emb + vv * En);
    const float4* w4 = (const float4*)(W_ih + h * En);
    float acc = 0.f;
    #pragma unroll
    for (int i = 0; i < En / 4; ++i) {
      float4 a = e4[i], b = w4[i];
      acc += a.x * b.x + a.y * b.y + a.z * b.z + a.w * b.w;
    }
    T2g[vv * Hn + perm(h)] = (_Float16)(acc + b_ih[h] + b_hh[h]);
  } else {
    int vv = bid - Vn, kp = tid;
    Wp[vv * Hn + kp] = (_Float16)W_ho[vv * Hn + iperm(kp)];
  }
}

// ---------- recurrence: 16 blocks x 256 thr (4 waves). Wave w: cols [64w,64w+64).
// One RAW barrier per step (lgkm drain only -- global exports never block).
// Zero global loads in the loop (idx bytes LDS-resident).
__global__ __launch_bounds__(256, 1) void k_rnn(const int* __restrict__ inp,
    const float* __restrict__ hidden, const float* __restrict__ W_hh,
    const _Float16* __restrict__ T2g, int haveT2g,
    const float* __restrict__ emb, const float* __restrict__ W_ih,
    const float* __restrict__ b_ih, const float* __restrict__ b_hh,
    float* out_base) {
  __shared__ _Float16 T2l[Vn * Hn];          // 64 KB  [v][k']
  __shared__ _Float16 Abuf[2 * 16 * Hn];     // 16 KB  [m][k'] swizzled, dbuf
  __shared__ unsigned char idxb[Sn * 16];    // 16 KB  [t][m]

  const int tid = threadIdx.x;
  const int l = tid & 63;
  const int w = tid >> 6;   // 0..3
  const int g = l >> 4;     // 0..3
  const int c = l & 15;
  const int bb0 = blockIdx.x << 4;

  // ---- stage T2 table
  if (haveT2g) {
    const uint4* src = (const uint4*)T2g;
    uint4* dst = (uint4*)T2l;
    #pragma unroll
    for (int i = 0; i < 16; ++i) dst[tid + (i << 8)] = src[tid + (i << 8)];
  } else {
    const int v = tid >> 1;
    const int h0 = (tid & 1) << 7;
    for (int hh = 0; hh < 128; ++hh) {
      int h = h0 + hh;
      const float4* e4 = (const float4*)(emb + v * En);
      const float4* w4 = (const float4*)(W_ih + h * En);
      float acc = 0.f;
      #pragma unroll
      for (int i = 0; i < En / 4; ++i) {
        float4 a = e4[i], b = w4[i];
        acc += a.x * b.x + a.y * b.y + a.z * b.z + a.w * b.w;
      }
      T2l[v * Hn + perm(h)] = (_Float16)(acc + b_ih[h] + b_hh[h]);
    }
  }

  // ---- stage idx bytes (V=128 fits u8)
  for (int m = 0; m < 16; ++m) {
    int4 d = ((const int4*)(inp + (size_t)(bb0 + m) * Sn))[tid];
    int t0 = tid << 2;
    idxb[(t0 + 0) * 16 + m] = (unsigned char)d.x;
    idxb[(t0 + 1) * 16 + m] = (unsigned char)d.y;
    idxb[(t0 + 2) * 16 + m] = (unsigned char)d.z;
    idxb[(t0 + 3) * 16 + m] = (unsigned char)d.w;
  }

  // ---- W_hh B-frags: Bf[cb][ks] elem j = W_hh[64w+16cb+c][iperm(32ks+8g+j)]
  f16x8 Bf[4][8];
  #pragma unroll
  for (int cb = 0; cb < 4; ++cb) {
    const float* wrow = W_hh + ((w << 6) + (cb << 4) + c) * Hn;
    #pragma unroll
    for (int ks = 0; ks < 8; ++ks) {
      union { _Float16 h[8]; f16x8 v8; } u;
      #pragma unroll
      for (int j = 0; j < 8; ++j)
        u.h[j] = (_Float16)wrow[iperm((ks << 5) + (g << 3) + j)];
      Bf[cb][ks] = u.v8;
    }
  }

  // per-thread LDS byte offsets (loop-invariant)
  const int xoff = (w << 7) + (c << 3);          // within-row byte off for x / h-write
  int awr[4];
  #pragma unroll
  for (int r = 0; r < 4; ++r) awr[r] = aswz((((g << 2) + r) << 9) + xoff);
  int ard[8];
  #pragma unroll
  for (int ks = 0; ks < 8; ++ks) ard[ks] = aswz((c << 9) + (ks << 6) + (g << 4));

  // ---- initial h -> Abuf buffer 0
  #pragma unroll
  for (int r = 0; r < 4; ++r) {
    int m = (g << 2) + r;
    f16x4 hp;
    #pragma unroll
    for (int cb = 0; cb < 4; ++cb)
      hp[cb] = (_Float16)hidden[(bb0 + m) * Hn + (w << 6) + (cb << 4) + c];
    *(u64*)((char*)Abuf + awr[r]) = *(u64*)&hp;
  }
  __syncthreads();

  _Float16* hallp = (_Float16*)out_base;
  float* hfin = out_base + (size_t)Bn * Sn * Vn;

  // export pointers, advanced by 256 f16 per step
  _Float16* hexp[4];
  #pragma unroll
  for (int r = 0; r < 4; ++r)
    hexp[r] = hallp + ((size_t)(bb0 + (g << 2) + r) * Sn) * 256 + (w << 6) + (c << 2);

  // x(0)
  f16x4 xv[4];
  {
    unsigned int iv = *(const unsigned int*)(idxb + (g << 2));
    #pragma unroll
    for (int r = 0; r < 4; ++r) {
      int v = (iv >> (r << 3)) & 255;
      xv[r] = *(const f16x4*)((const char*)T2l + v * 512 + xoff);
    }
  }

  #pragma unroll 1
  for (int t = 0; t < Sn; ++t) {
    const int roff = (t & 1) << 13;
    const int woff = roff ^ 8192;

    // A-frag reads + MFMA (split-K: two 4-deep chains per cb)
    f32x4 aA[4] = {{0,0,0,0},{0,0,0,0},{0,0,0,0},{0,0,0,0}};
    f32x4 aB[4] = {{0,0,0,0},{0,0,0,0},{0,0,0,0},{0,0,0,0}};
    const char* ab = (const char*)Abuf + roff;
    #pragma unroll
    for (int ks = 0; ks < 4; ++ks) {
      f16x8 af = *(const f16x8*)(ab + ard[ks]);
      aA[0] = __builtin_amdgcn_mfma_f32_16x16x32_f16(af, Bf[0][ks], aA[0], 0, 0, 0);
      aA[1] = __builtin_amdgcn_mfma_f32_16x16x32_f16(af, Bf[1][ks], aA[1], 0, 0, 0);
      aA[2] = __builtin_amdgcn_mfma_f32_16x16x32_f16(af, Bf[2][ks], aA[2], 0, 0, 0);
      aA[3] = __builtin_amdgcn_mfma_f32_16x16x32_f16(af, Bf[3][ks], aA[3], 0, 0, 0);
    }
    #pragma unroll
    for (int ks = 4; ks < 8; ++ks) {
      f16x8 af = *(const f16x8*)(ab + ard[ks]);
      aB[0] = __builtin_amdgcn_mfma_f32_16x16x32_f16(af, Bf[0][ks], aB[0], 0, 0, 0);
      aB[1] = __builtin_amdgcn_mfma_f32_16x16x32_f16(af, Bf[1][ks], aB[1], 0, 0, 0);
      aB[2] = __builtin_amdgcn_mfma_f32_16x16x32_f16(af, Bf[2][ks], aB[2], 0, 0, 0);
      aB[3] = __builtin_amdgcn_mfma_f32_16x16x32_f16(af, Bf[3][ks], aB[3], 0, 0, 0);
    }

    // prefetch x(t+1): idx dword then 4 x b64 (hidden under MFMA phase)
    int tn = (t + 1 < Sn) ? t + 1 : t;
    f16x4 xn[4];
    {
      unsigned int iv = *(const unsigned int*)(idxb + tn * 16 + (g << 2));
      #pragma unroll
      for (int r = 0; r < 4; ++r) {
        int v = (iv >> (r << 3)) & 255;
        xn[r] = *(const f16x4*)((const char*)T2l + v * 512 + xoff);
      }
    }

    // epilogue: z, tanh, pack; h-write (LDS, dbuf) + export (global, no wait)
    char* wb = (char*)Abuf + woff;
    #pragma unroll
    for (int r = 0; r < 4; ++r) {
      f16x4 hp;
      #pragma unroll
      for (int cb = 0; cb < 4; ++cb) {
        float z = (aA[cb][r] + aB[cb][r]) + (float)xv[r][cb];
        hp[cb] = (_Float16)tanh_fast(z);
      }
      *(u64*)(wb + awr[r]) = *(u64*)&hp;
      *(f16x4*)hexp[r] = hp;
      hexp[r] += 256;
    }
    #pragma unroll
    for (int r = 0; r < 4; ++r) xv[r] = xn[r];

    // RAW barrier: LDS drain only -- global exports stay in flight
    asm volatile("s_waitcnt lgkmcnt(0)\n\ts_barrier" ::: "memory");
  }

  // h_final from the final LDS buffer (buffer 0 after t=1023), f16->f32
  #pragma unroll
  for (int r = 0; r < 4; ++r) {
    int m = (g << 2) + r;
    f16x4 hp = *(const f16x4*)((const char*)Abuf + awr[r]);
    #pragma unroll
    for (int cb = 0; cb < 4; ++cb)
      hfin[(bb0 + m) * Hn + (w << 6) + (cb << 4) + c] = (float)hp[cb];
  }
}

// ---------- output GEMM: 4096 blocks x 512 thr (8 waves), in place over d_out.
// FAST (Wp != null): B-frags straight from permuted f16 Wp in global (L2-hot).
// SLOW: stage W_ho into LDS (permuted+swizzled) once per block.
template <int SLOW>
__global__ __launch_bounds__(512) void k_out(const float* __restrict__ W_ho,
    const float* __restrict__ b_ho, const _Float16* __restrict__ Wp,
    float* out_base) {
  __shared__ _Float16 At[64 * 256];                 // 32 KB, row-swizzled
  __shared__ _Float16 Wl[SLOW ? Vn * Hn : 8];       // 64 KB slow path only
  const int tid = threadIdx.x;
  const int l = tid & 63;
  const int w = tid >> 6;   // 0..7
  const int g = l >> 4;
  const int c = l & 15;
  const size_t m0 = (size_t)blockIdx.x << 6;
  const _Float16* hall = (const _Float16*)out_base;

  // stage A tile (reads f16 overlay of rows we will overwrite after the barrier)
  {
    const uint4* src = (const uint4*)(hall + (m0 << 8));
    #pragma unroll
    for (int i = 0; i < 4; ++i) {
      int gg = tid + (i << 9);
      int row = gg >> 5;
      int cb16 = (gg & 31) << 4;
      uint4 d = src[gg];
      *(uint4*)((char*)At + ((row * 512 + cb16) ^ ((row & 7) << 4))) = d;
    }
  }

  const int v = (w << 4) + c;
  f16x8 Bf[8];
  if (!SLOW) {
    const _Float16* wrow = Wp + v * Hn;
    #pragma unroll
    for (int ks = 0; ks < 8; ++ks)
      Bf[ks] = *(const f16x8*)(wrow + (ks << 5) + (g << 3));
    __syncthreads();
  } else {
    {
      int sv = tid >> 2;
      int kc = (tid & 3) << 6;
      const float* srcw = W_ho + sv * Hn + kc;
      for (int e = 0; e < 64; ++e) {
        int k = kc + e;
        *(_Float16*)((char*)Wl + ((sv * 512 + (perm(k) << 1)) ^ ((sv & 7) << 4)))
            = (_Float16)srcw[e];
      }
    }
    __syncthreads();
    #pragma unroll
    for (int ks = 0; ks < 8; ++ks)
      Bf[ks] = *(const f16x8*)((const char*)Wl +
                 ((v * 512 + (ks << 6) + (g << 4)) ^ ((v & 7) << 4)));
  }
  const float bias = b_ho[v];

  #pragma unroll
  for (int mt = 0; mt < 4; ++mt) {
    f32x4 acc = {bias, bias, bias, bias};
    const int row = (mt << 4) + c;
    #pragma unroll
    for (int ks = 0; ks < 8; ++ks) {
      f16x8 a = *(const f16x8*)((const char*)At +
                  ((row * 512 + (ks << 6) + (g << 4)) ^ ((row & 7) << 4)));
      acc = __builtin_amdgcn_mfma_f32_16x16x32_f16(a, Bf[ks], acc, 0, 0, 0);
    }
    float* orow = out_base + (m0 + (mt << 4) + (g << 2)) * Vn + v;
    orow[0]      = acc[0];
    orow[Vn]     = acc[1];
    orow[2 * Vn] = acc[2];
    orow[3 * Vn] = acc[3];
  }
}

extern "C" void kernel_launch(void* const* d_in, const int* in_sizes, int n_in,
                              void* d_out, int out_size, void* d_ws, size_t ws_size,
                              hipStream_t stream) {
  (void)in_sizes; (void)n_in; (void)out_size;
  const int*   inp    = (const int*)  d_in[0];
  const float* hidden = (const float*)d_in[1];
  const float* emb    = (const float*)d_in[2];
  const float* W_ih   = (const float*)d_in[3];
  const float* b_ih   = (const float*)d_in[4];
  const float* W_hh   = (const float*)d_in[5];
  const float* b_hh   = (const float*)d_in[6];
  const float* W_ho   = (const float*)d_in[7];
  const float* b_ho   = (const float*)d_in[8];
  float* out = (float*)d_out;

  const bool useWs = (ws_size >= 131072);
  _Float16* T2g = useWs ? (_Float16*)d_ws : nullptr;
  _Float16* Wp  = useWs ? (_Float16*)((char*)d_ws + 65536) : nullptr;

  if (useWs)
    k_prep<<<dim3(2 * Vn), dim3(Hn), 0, stream>>>(emb, W_ih, b_ih, b_hh, W_ho, T2g, Wp);

  k_rnn<<<dim3(Bn / 16), dim3(256), 0, stream>>>(inp, hidden, W_hh, T2g,
                                                 useWs ? 1 : 0,
                                                 emb, W_ih, b_ih, b_hh, out);
  if (useWs)
    k_out<0><<<dim3((Bn * Sn) / 64), dim3(512), 0, stream>>>(W_ho, b_ho, Wp, out);
  else
    k_out<1><<<dim3((Bn * Sn) / 64), dim3(512), 0, stream>>>(W_ho, b_ho, nullptr, out);
}